// Round 22
// baseline (3102.459 us; speedup 1.0000x reference)
//
#include <hip/hip_runtime.h>

typedef __attribute__((ext_vector_type(8))) __bf16 bf16x8;
typedef __attribute__((ext_vector_type(16))) float f32x16;

#define DEV __device__ __forceinline__

DEV unsigned short f2bf(float f) {
  unsigned int u = __float_as_uint(f);
  u += 0x7FFFu + ((u >> 16) & 1u);   // RNE
  return (unsigned short)(u >> 16);
}

// Branch-free tanh-form GELU (~10 VALU ops, no divergence).
DEV float gelu_fast(float v) {
  float x2 = v * v;
  float u = v * (0.7978845608028654f + 0.035677408136300125f * x2);
  u = fminf(fmaxf(u, -9.f), 9.f);
  float e = __expf(2.f * u);
  float th = (e - 1.f) / (e + 1.f);
  return 0.5f * v * (1.f + th);
}

// ---------------- kernel 1: f32 -> bf16 (vectorized) ----------------
__global__ __launch_bounds__(256) void k_f32_to_bf16(const float* __restrict__ x,
                                                     unsigned short* __restrict__ y) {
  size_t i = ((size_t)blockIdx.x * 256 + threadIdx.x) * 8;
  float4 a = *(const float4*)(x + i);
  float4 b = *(const float4*)(x + i + 4);
  union { unsigned short u[8]; uint4 v; } o;
  o.u[0] = f2bf(a.x); o.u[1] = f2bf(a.y); o.u[2] = f2bf(a.z); o.u[3] = f2bf(a.w);
  o.u[4] = f2bf(b.x); o.u[5] = f2bf(b.y); o.u[6] = f2bf(b.z); o.u[7] = f2bf(b.w);
  *(uint4*)(y + i) = o.v;
}

// ------- kernel 2: AWQ int4 dequant -> W^T bf16 [N][K] (LDS transpose) -------
__global__ __launch_bounds__(256) void k_dequant_t(const int* __restrict__ qw,
                                                   const int* __restrict__ qz,
                                                   const float* __restrict__ sc,
                                                   unsigned short* __restrict__ wt,
                                                   int K, int N) {
  __shared__ __align__(16) unsigned short st[64][72];
  const int k0 = blockIdx.x * 64, n0 = blockIdx.y * 64;
  const int t = threadIdx.x;
  const int g = k0 >> 7;
  const int Np = N >> 3;
#pragma unroll
  for (int it = 0; it < 2; ++it) {
    int idx = t + it * 256;
    int k = idx >> 3;
    int nc = idx & 7;
    unsigned int w = (unsigned int)qw[(size_t)(k0 + k) * Np + (n0 >> 3) + nc];
    unsigned int z = (unsigned int)qz[(size_t)g * Np + (n0 >> 3) + nc];
#pragma unroll
    for (int i = 0; i < 8; ++i) {
      float s = sc[(size_t)g * N + n0 + nc * 8 + i];
      float v = ((float)(int)((w >> (4 * i)) & 0xFu) -
                 (float)(int)((z >> (4 * i)) & 0xFu)) * s;
      st[nc * 8 + i][k] = f2bf(v);
    }
  }
  __syncthreads();
  const int n = t >> 2, c = t & 3;
  uint4 v0 = *(const uint4*)&st[n][c * 16];
  uint4 v1 = *(const uint4*)&st[n][c * 16 + 8];
  unsigned short* dst = wt + (size_t)(n0 + n) * K + k0 + c * 16;
  *(uint4*)dst = v0;
  *(uint4*)(dst + 8) = v1;
}

// ------ kernel 3: 256x256 GEMM, 32x32x16 MFMA, FRAGMENT-LINEAR LDS -----------
// R21 post-mortem: 32x32 frag reads hit 1.007e8 bank-conflict cycles (=164us
// per GEMM, exactly the R17->R21 regression); two hand bank-models failed to
// predict it. Fix: conflict-free BY CONSTRUCTION -- store each 16KB slab in
// MFMA-fragment order. 16B unit u = (frag*2 + kstep)*64 + lane, so every
// frag read is ds_read_b128 at wave-uniform base + lane*16 (same linear
// pattern as the DMA write => conflict-free like coalesced). Bijective decode
// u -> (row, k8): row = (u>>7)*32 + (u&31); k8 = ((u>>6)&1)*2 + ((u>>5)&1);
// unit tid+512 = row+128, so staging keeps the two-DMA (+128*K) form. No XOR
// swizzle anywhere. R17 sync structure (1 sync/tile), raster, gelu_fast, and
// R21's verified 32x32 C/D epilogue unchanged.

#define STAGE_A(h) do { const unsigned short* g_ = A + gsA + (size_t)(h) * 32;               \
  __builtin_amdgcn_global_load_lds((const __attribute__((address_space(1))) void*)g_,        \
      (__attribute__((address_space(3))) void*)(&sA[(h) & 3][0] + tid * 8), 16, 0, 0);       \
  __builtin_amdgcn_global_load_lds((const __attribute__((address_space(1))) void*)(g_ + (size_t)128 * K), \
      (__attribute__((address_space(3))) void*)(&sA[(h) & 3][4096] + tid * 8), 16, 0, 0); } while (0)
#define STAGE_B(h) do { const unsigned short* g_ = B + gsB + (size_t)(h) * 32;               \
  __builtin_amdgcn_global_load_lds((const __attribute__((address_space(1))) void*)g_,        \
      (__attribute__((address_space(3))) void*)(&sB[(h) & 3][0] + tid * 8), 16, 0, 0);       \
  __builtin_amdgcn_global_load_lds((const __attribute__((address_space(1))) void*)(g_ + (size_t)128 * K), \
      (__attribute__((address_space(3))) void*)(&sB[(h) & 3][4096] + tid * 8), 16, 0, 0); } while (0)

// fragment-linear reads: wave-uniform frag base + lane*16B (in shorts: *8)
#define LDA32(s, mi, st) (*(const bf16x8*)(&sA[s][0] + (((wm * 4 + (mi)) * 2 + ((st) & 1)) * 64 + lane) * 8))
#define LDB32(s, nj, st) (*(const bf16x8*)(&sB[s][0] + (((wn * 2 + (nj)) * 2 + ((st) & 1)) * 64 + lane) * 8))

template <int GELU>
__global__ __launch_bounds__(512, 2) void k_gemm256(const unsigned short* __restrict__ A,
                                                    const unsigned short* __restrict__ B,
                                                    void* __restrict__ C,
                                                    int M, int N, int K) {
  __shared__ __align__(16) unsigned short sA[4][8192];
  __shared__ __align__(16) unsigned short sB[4][8192];
  const int tid = threadIdx.x;
  const int lane = tid & 63;
  const int wave = tid >> 6;
  const int wm = wave >> 2, wn = wave & 3;
  const int l31 = lane & 31;

  // Raster: bijective XCD chunk + grouped-m (GM=16, m-fastest within group).
  const int nbx = N >> 8;
  const int cpx = gridDim.x >> 3;
  const int g = (blockIdx.x & 7) * cpx + (blockIdx.x >> 3);
  const int gw = nbx << 4;
  const int grp = g / gw;
  const int rem = g - grp * gw;
  const int m0 = (grp * 16 + (rem & 15)) * 256;
  const int n0 = (rem >> 4) * 256;

  // staging decode: unit u = tid -> (row, k8); unit tid+512 = row+128, same k8
  const int srow = ((tid >> 7) << 5) | (tid & 31);
  const int sk8  = ((tid >> 6) & 1) * 2 + ((tid >> 5) & 1);
  const size_t gsA = (size_t)(m0 + srow) * K + (size_t)sk8 * 8;
  const size_t gsB = (size_t)(n0 + srow) * K + (size_t)sk8 * 8;

  f32x16 acc[4][2] = {};
  bf16x8 af[4][4], bf[4][2];
  const int NT = K >> 6;

  // prologue: stage slabs 0,1 (slots 0,1); loop-top sync covers the rest
  STAGE_A(0); STAGE_B(0); STAGE_A(1); STAGE_B(1);

  for (int t = 0; t < NT; ++t) {
    const int s0 = (2 * t) & 3, s1 = (2 * t + 1) & 3;

    // ---- single sync per tile: own-DMA drain, then publish via barrier
    asm volatile("s_waitcnt vmcnt(0)" ::: "memory");
    __builtin_amdgcn_s_barrier();

    // ---- 24 frag reads (linear, conflict-free): steps 0,1 slab s0; 2,3 s1
#pragma unroll
    for (int st = 0; st < 4; ++st) {
      const int sl = (st < 2) ? s0 : s1;
#pragma unroll
      for (int nj = 0; nj < 2; ++nj) bf[st][nj] = LDB32(sl, nj, st);
#pragma unroll
      for (int mi = 0; mi < 4; ++mi) af[st][mi] = LDA32(sl, mi, st);
    }

    // ---- stage next tile's slabs into the other two ring slots
    if (t < NT - 1) {
      STAGE_A(2 * t + 2); STAGE_B(2 * t + 2);
      STAGE_A(2 * t + 3); STAGE_B(2 * t + 3);
    }

    // ---- 32 MFMA (first cluster starts as soon as its 6 reads land)
    __builtin_amdgcn_s_setprio(1);
#pragma unroll
    for (int st = 0; st < 4; ++st)
#pragma unroll
      for (int mi = 0; mi < 4; ++mi)
#pragma unroll
        for (int nj = 0; nj < 2; ++nj)
          acc[mi][nj] = __builtin_amdgcn_mfma_f32_32x32x16_bf16(af[st][mi], bf[st][nj], acc[mi][nj], 0, 0, 0);
    __builtin_amdgcn_s_setprio(0);
  }

  // epilogue: 32x32 C/D layout col=lane&31, row=(reg&3)+8*(reg>>2)+4*(lane>>5)
  const int mb = m0 + wm * 128 + 4 * (lane >> 5);
  const int nb = n0 + wn * 64 + l31;
#pragma unroll
  for (int mi = 0; mi < 4; ++mi) {
#pragma unroll
    for (int nj = 0; nj < 2; ++nj) {
#pragma unroll
      for (int r = 0; r < 16; ++r) {
        int row = mb + mi * 32 + (r & 3) + 8 * (r >> 2);
        int col = nb + nj * 32;
        float v = acc[mi][nj][r];
        if (GELU) {
          v = gelu_fast(v);
          ((unsigned short*)C)[(size_t)row * N + col] = f2bf(v);
        } else {
          ((float*)C)[(size_t)row * N + col] = v;
        }
      }
    }
  }
}

extern "C" void kernel_launch(void* const* d_in, const int* in_sizes, int n_in,
                              void* d_out, int out_size, void* d_ws, size_t ws_size,
                              hipStream_t stream) {
  const float* x  = (const float*)d_in[0];
  const int* uqw  = (const int*)d_in[1];
  const int* uqz  = (const int*)d_in[2];
  const float* usc = (const float*)d_in[3];
  const int* dqw  = (const int*)d_in[4];
  const int* dqz  = (const int*)d_in[5];
  const float* dsc = (const float*)d_in[6];
  float* out = (float*)d_out;

  const int T = 8192, D = 4096, F = 16384;
  char* ws = (char*)d_ws;
  unsigned short* xb = (unsigned short*)ws;                                  // 64 MiB
  unsigned short* h  = (unsigned short*)(ws + (size_t)T * D * 2);            // 256 MiB
  unsigned short* wt = (unsigned short*)(ws + (size_t)T * D * 2 + (size_t)T * F * 2); // 128 MiB

  k_f32_to_bf16<<<dim3((T * D) / (256 * 8)), 256, 0, stream>>>(x, xb);
  k_dequant_t<<<dim3(D / 64, F / 64), 256, 0, stream>>>(uqw, uqz, usc, wt, D, F);
  k_gemm256<1><<<dim3((T / 256) * (F / 256)), 512, 0, stream>>>(xb, wt, (void*)h, T, F, D);
  k_dequant_t<<<dim3(F / 64, D / 64), 256, 0, stream>>>(dqw, dqz, dsc, wt, F, D);
  k_gemm256<0><<<dim3((T / 256) * (D / 256)), 512, 0, stream>>>(h, wt, (void*)out, T, D, F);
}

// Round 23
// 2127.026 us; speedup vs baseline: 1.4586x; 1.4586x over previous
//
#include <hip/hip_runtime.h>

typedef __attribute__((ext_vector_type(8))) __bf16 bf16x8;
typedef __attribute__((ext_vector_type(4))) float f32x4;

#define DEV __device__ __forceinline__

DEV unsigned short f2bf(float f) {
  unsigned int u = __float_as_uint(f);
  u += 0x7FFFu + ((u >> 16) & 1u);   // RNE
  return (unsigned short)(u >> 16);
}

// Branch-free tanh-form GELU (~10 VALU ops, no divergence).
DEV float gelu_fast(float v) {
  float x2 = v * v;
  float u = v * (0.7978845608028654f + 0.035677408136300125f * x2);
  u = fminf(fmaxf(u, -9.f), 9.f);
  float e = __expf(2.f * u);
  float th = (e - 1.f) / (e + 1.f);
  return 0.5f * v * (1.f + th);
}

// ---------------- kernel 1: f32 -> bf16 (vectorized) ----------------
__global__ __launch_bounds__(256) void k_f32_to_bf16(const float* __restrict__ x,
                                                     unsigned short* __restrict__ y) {
  size_t i = ((size_t)blockIdx.x * 256 + threadIdx.x) * 8;
  float4 a = *(const float4*)(x + i);
  float4 b = *(const float4*)(x + i + 4);
  union { unsigned short u[8]; uint4 v; } o;
  o.u[0] = f2bf(a.x); o.u[1] = f2bf(a.y); o.u[2] = f2bf(a.z); o.u[3] = f2bf(a.w);
  o.u[4] = f2bf(b.x); o.u[5] = f2bf(b.y); o.u[6] = f2bf(b.z); o.u[7] = f2bf(b.w);
  *(uint4*)(y + i) = o.v;
}

// ------- kernel 2: AWQ int4 dequant -> W^T bf16 [N][K] (LDS transpose) -------
__global__ __launch_bounds__(256) void k_dequant_t(const int* __restrict__ qw,
                                                   const int* __restrict__ qz,
                                                   const float* __restrict__ sc,
                                                   unsigned short* __restrict__ wt,
                                                   int K, int N) {
  __shared__ __align__(16) unsigned short st[64][72];
  const int k0 = blockIdx.x * 64, n0 = blockIdx.y * 64;
  const int t = threadIdx.x;
  const int g = k0 >> 7;
  const int Np = N >> 3;
#pragma unroll
  for (int it = 0; it < 2; ++it) {
    int idx = t + it * 256;
    int k = idx >> 3;
    int nc = idx & 7;
    unsigned int w = (unsigned int)qw[(size_t)(k0 + k) * Np + (n0 >> 3) + nc];
    unsigned int z = (unsigned int)qz[(size_t)g * Np + (n0 >> 3) + nc];
#pragma unroll
    for (int i = 0; i < 8; ++i) {
      float s = sc[(size_t)g * N + n0 + nc * 8 + i];
      float v = ((float)(int)((w >> (4 * i)) & 0xFu) -
                 (float)(int)((z >> (4 * i)) & 0xFu)) * s;
      st[nc * 8 + i][k] = f2bf(v);
    }
  }
  __syncthreads();
  const int n = t >> 2, c = t & 3;
  uint4 v0 = *(const uint4*)&st[n][c * 16];
  uint4 v1 = *(const uint4*)&st[n][c * 16 + 8];
  unsigned short* dst = wt + (size_t)(n0 + n) * K + k0 + c * 16;
  *(uint4*)dst = v0;
  *(uint4*)(dst + 8) = v1;
}

// ------ kernel 3: 256x256 GEMM, ONE sync per K-tile (R17 champion) -----------
// R22 post-mortem: 32x32 family closed -- fragment-linear LDS killed DMA
// coalescing (32B/row segments, FETCH +40%, latency-starved); R21's row-major
// 32x32 reads conflicted (1e8 cyc). Structural: conflict-free 32x32 frag
// reads and 64B-coalesced global_load_lds staging are mutually exclusive
// (linear-dest rule). 16x16 pattern is conflict-free AND coalesced.
// This is the measured local optimum after 12 refuted levers: rasters,
// vmcnt depth/flight, A-from-global, 2 blocks/CU, occupancy-max, phase
// schedules, split clusters, 32x32 shape. Sync spacing is LDS-capacity-
// bound (wider needs >160KB ring). ~1.05 PF effective per GEMM.

#define STAGE_A(h) do { const unsigned short* g_ = A + gsA + (size_t)(h) * 32;               \
  __builtin_amdgcn_global_load_lds((const __attribute__((address_space(1))) void*)g_,        \
      (__attribute__((address_space(3))) void*)(&sA[(h) & 3][0] + tid * 8), 16, 0, 0);       \
  __builtin_amdgcn_global_load_lds((const __attribute__((address_space(1))) void*)(g_ + (size_t)128 * K), \
      (__attribute__((address_space(3))) void*)(&sA[(h) & 3][4096] + tid * 8), 16, 0, 0); } while (0)
#define STAGE_B(h) do { const unsigned short* g_ = B + gsB + (size_t)(h) * 32;               \
  __builtin_amdgcn_global_load_lds((const __attribute__((address_space(1))) void*)g_,        \
      (__attribute__((address_space(3))) void*)(&sB[(h) & 3][0] + tid * 8), 16, 0, 0);       \
  __builtin_amdgcn_global_load_lds((const __attribute__((address_space(1))) void*)(g_ + (size_t)128 * K), \
      (__attribute__((address_space(3))) void*)(&sB[(h) & 3][4096] + tid * 8), 16, 0, 0); } while (0)

#define LDA(s, m) (*(const bf16x8*)((const char*)&sA[s][0] + offA + (m) * 1024))
#define LDB(s, n) (*(const bf16x8*)((const char*)&sB[s][0] + offB + (n) * 1024))

template <int GELU>
__global__ __launch_bounds__(512, 2) void k_gemm256(const unsigned short* __restrict__ A,
                                                    const unsigned short* __restrict__ B,
                                                    void* __restrict__ C,
                                                    int M, int N, int K) {
  __shared__ __align__(16) unsigned short sA[4][8192];
  __shared__ __align__(16) unsigned short sB[4][8192];
  const int tid = threadIdx.x;
  const int lane = tid & 63;
  const int wave = tid >> 6;
  const int wm = wave >> 2, wn = wave & 3;
  const int r16 = lane & 15, q = lane >> 4;

  // Raster: bijective XCD chunk + grouped-m (GM=16, m-fastest within group).
  const int nbx = N >> 8;
  const int cpx = gridDim.x >> 3;
  const int g = (blockIdx.x & 7) * cpx + (blockIdx.x >> 3);
  const int gw = nbx << 4;
  const int grp = g / gw;
  const int rem = g - grp * gw;
  const int m0 = (grp * 16 + (rem & 15)) * 256;
  const int n0 = (rem >> 4) * 256;

  const int rA = wm * 128 + r16;
  const int rB = wn * 64 + r16;
  const int offA = rA * 64 + ((q * 16) ^ (((rA >> 1) & 3) << 4));
  const int offB = rB * 64 + ((q * 16) ^ (((rB >> 1) & 3) << 4));

  const int sr = tid >> 2;                        // staging row (0..127)
  const int ssrc = (tid & 3) ^ ((sr >> 1) & 3);   // pre-swizzled global 16B slot
  const size_t gsA = (size_t)(m0 + sr) * K + (size_t)ssrc * 8;
  const size_t gsB = (size_t)(n0 + sr) * K + (size_t)ssrc * 8;

  f32x4 acc[8][4] = {};
  bf16x8 pA0[8], pB0[4], pA1[8], pB1[4];
  const int NT = K >> 6;

  // prologue: stage slabs 0,1 (slots 0,1); loop-top sync covers the rest
  STAGE_A(0); STAGE_B(0); STAGE_A(1); STAGE_B(1);

  for (int t = 0; t < NT; ++t) {
    const int s0 = (2 * t) & 3, s1 = (2 * t + 1) & 3;

    // ---- single sync per tile: own-DMA drain, then publish via barrier
    asm volatile("s_waitcnt vmcnt(0)" ::: "memory");
    __builtin_amdgcn_s_barrier();

    // ---- 24 frag reads: slab 2t -> p0, slab 2t+1 -> p1
#pragma unroll
    for (int i = 0; i < 8; ++i) pA0[i] = LDA(s0, i);
#pragma unroll
    for (int j = 0; j < 4; ++j) pB0[j] = LDB(s0, j);
#pragma unroll
    for (int i = 0; i < 8; ++i) pA1[i] = LDA(s1, i);
#pragma unroll
    for (int j = 0; j < 4; ++j) pB1[j] = LDB(s1, j);

    // ---- stage next tile's slabs into the other two ring slots
    if (t < NT - 1) {
      STAGE_A(2 * t + 2); STAGE_B(2 * t + 2);
      STAGE_A(2 * t + 3); STAGE_B(2 * t + 3);
    }

    // ---- 64 MFMA (p0 cluster starts as soon as its 12 reads land)
    __builtin_amdgcn_s_setprio(1);
#pragma unroll
    for (int i = 0; i < 8; ++i)
#pragma unroll
      for (int j = 0; j < 4; ++j)
        acc[i][j] = __builtin_amdgcn_mfma_f32_16x16x32_bf16(pA0[i], pB0[j], acc[i][j], 0, 0, 0);
#pragma unroll
    for (int i = 0; i < 8; ++i)
#pragma unroll
      for (int j = 0; j < 4; ++j)
        acc[i][j] = __builtin_amdgcn_mfma_f32_16x16x32_bf16(pA1[i], pB1[j], acc[i][j], 0, 0, 0);
    __builtin_amdgcn_s_setprio(0);
  }

  // epilogue: C/D layout col=lane&15, row=(lane>>4)*4+reg
  const int mb = m0 + wm * 128 + q * 4;
  const int nb = n0 + wn * 64 + r16;
#pragma unroll
  for (int i = 0; i < 8; ++i) {
#pragma unroll
    for (int j = 0; j < 4; ++j) {
#pragma unroll
      for (int r = 0; r < 4; ++r) {
        int row = mb + i * 16 + r;
        int col = nb + j * 16;
        float v = acc[i][j][r];
        if (GELU) {
          v = gelu_fast(v);
          ((unsigned short*)C)[(size_t)row * N + col] = f2bf(v);
        } else {
          ((float*)C)[(size_t)row * N + col] = v;
        }
      }
    }
  }
}

extern "C" void kernel_launch(void* const* d_in, const int* in_sizes, int n_in,
                              void* d_out, int out_size, void* d_ws, size_t ws_size,
                              hipStream_t stream) {
  const float* x  = (const float*)d_in[0];
  const int* uqw  = (const int*)d_in[1];
  const int* uqz  = (const int*)d_in[2];
  const float* usc = (const float*)d_in[3];
  const int* dqw  = (const int*)d_in[4];
  const int* dqz  = (const int*)d_in[5];
  const float* dsc = (const float*)d_in[6];
  float* out = (float*)d_out;

  const int T = 8192, D = 4096, F = 16384;
  char* ws = (char*)d_ws;
  unsigned short* xb = (unsigned short*)ws;                                  // 64 MiB
  unsigned short* h  = (unsigned short*)(ws + (size_t)T * D * 2);            // 256 MiB
  unsigned short* wt = (unsigned short*)(ws + (size_t)T * D * 2 + (size_t)T * F * 2); // 128 MiB

  k_f32_to_bf16<<<dim3((T * D) / (256 * 8)), 256, 0, stream>>>(x, xb);
  k_dequant_t<<<dim3(D / 64, F / 64), 256, 0, stream>>>(uqw, uqz, usc, wt, D, F);
  k_gemm256<1><<<dim3((T / 256) * (F / 256)), 512, 0, stream>>>(xb, wt, (void*)h, T, F, D);
  k_dequant_t<<<dim3(F / 64, D / 64), 256, 0, stream>>>(dqw, dqz, dsc, wt, F, D);
  k_gemm256<0><<<dim3((T / 256) * (D / 256)), 512, 0, stream>>>(h, wt, (void*)out, T, D, F);
}